// Round 7
// baseline (186.662 us; speedup 1.0000x reference)
//
#include <hip/hip_runtime.h>

#define BATCH 4096
#define N 64

// One DPP unsigned-max step: x = max(x, dpp_move(x)). VALU only, no DS ops.
template<int CTRL>
__device__ __forceinline__ unsigned dpp_umax(unsigned x) {
    unsigned moved = (unsigned)__builtin_amdgcn_update_dpp(0, (int)x, CTRL, 0xf, 0xf, true);
    return (moved > x) ? moved : x;
}

// Broadcast a float from wave-uniform lane ps via v_readlane (SGPR result,
// folds as the scalar operand of the consuming v_fma).
__device__ __forceinline__ float lanebcastf(float v, int ps) {
    return __uint_as_float(__builtin_amdgcn_readlane(__float_as_uint(v), ps));
}

// One wave per sample; the sample's TWO determinants (up & dn) are computed
// INTERLEAVED so each det's serial pivot chain (6 dependent DPP maxes +
// readlane + rcp) overlaps with the other det's independent work.
// Argmax trick: key = (bits(|a[k]|) & ~63) | lane is monotone in |a[k]|
// (floats >= 0 compare as uints), so one umax-reduce + one readlane yields
// both the max and the pivot lane -- no ballot / VALU->SALU round-trip.
__global__ __launch_bounds__(64)
__attribute__((amdgpu_waves_per_eu(1, 4)))
void restricted_det_kernel(
    const float* __restrict__ U,
    const int* __restrict__ idx_up,
    const int* __restrict__ idx_dn,
    float* __restrict__ out)
{
    const int lane = threadIdx.x;      // 0..63, one wave per block
    const int wid  = blockIdx.x;       // sample id

    const int siteA = idx_up[wid * N + lane];
    const int siteB = idx_dn[wid * N + lane];

    // lane i holds row i of BOTH gathered matrices, in registers
    float aA[N], aB[N];
    {
        const float4* __restrict__ ra = reinterpret_cast<const float4*>(U + (long)siteA * N);
        const float4* __restrict__ rb = reinterpret_cast<const float4*>(U + (long)siteB * N);
        #pragma unroll
        for (int q = 0; q < N / 4; ++q) {
            float4 va = ra[q];
            float4 vb = rb[q];
            aA[4*q+0]=va.x; aA[4*q+1]=va.y; aA[4*q+2]=va.z; aA[4*q+3]=va.w;
            aB[4*q+0]=vb.x; aB[4*q+1]=vb.y; aB[4*q+2]=vb.z; aB[4*q+3]=vb.w;
        }
    }

    float l2sum = 0.0f;                 // sum log2|pivot| over both dets
    unsigned sbits = 0u;                // xor of pivot sign bits (uniform)
    int inv = 0;                        // inversion count (uniform)
    unsigned long long chosenA = 0ull, chosenB = 0ull;
    bool aliveA = true, aliveB = true;  // i1 -> lane-mask in SGPR pair

    #pragma unroll
    for (int k = 0; k < N; ++k) {
        // ---- packed keys (off-chain alive mask via cndmask) ----
        unsigned tA = (__float_as_uint(aA[k]) & 0x7FFFFFC0u) | (unsigned)lane;
        unsigned tB = (__float_as_uint(aB[k]) & 0x7FFFFFC0u) | (unsigned)lane;
        unsigned rA = aliveA ? tA : 0u;
        unsigned rB = aliveB ? tB : 0u;

        // ---- two independent DPP umax chains, source-interleaved ----
        rA = dpp_umax<0x111>(rA); rB = dpp_umax<0x111>(rB);   // row_shr:1
        rA = dpp_umax<0x112>(rA); rB = dpp_umax<0x112>(rB);   // row_shr:2
        rA = dpp_umax<0x114>(rA); rB = dpp_umax<0x114>(rB);   // row_shr:4
        rA = dpp_umax<0x118>(rA); rB = dpp_umax<0x118>(rB);   // row_shr:8
        rA = dpp_umax<0x142>(rA); rB = dpp_umax<0x142>(rB);   // row_bcast:15
        rA = dpp_umax<0x143>(rA); rB = dpp_umax<0x143>(rB);   // row_bcast:31

        const unsigned winA = (unsigned)__builtin_amdgcn_readlane((int)rA, 63);
        const unsigned winB = (unsigned)__builtin_amdgcn_readlane((int)rB, 63);
        const int psA = (int)(winA & 63u);    // uniform pivot lanes (SALU)
        const int psB = (int)(winB & 63u);

        // ---- parity bookkeeping (SALU, off-chain) ----
        inv += __popcll(chosenA >> psA);  chosenA |= (1ull << psA);
        inv += __popcll(chosenB >> psB);  chosenB |= (1ull << psB);
        aliveA = aliveA && (lane != psA);
        aliveB = aliveB && (lane != psB);

        // ---- pivot values: sign xor + log2 accumulation (off-chain) ----
        const float pvA = lanebcastf(aA[k], psA);
        const float pvB = lanebcastf(aB[k], psB);
        sbits ^= __float_as_uint(pvA) & 0x80000000u;
        sbits ^= __float_as_uint(pvB) & 0x80000000u;
        l2sum += __log2f(__builtin_fabsf(pvA));
        l2sum += __log2f(__builtin_fabsf(pvB));

        // ---- multipliers (dead/pivot lanes free-run on garbage; safe:
        //      each pivot-row elem is readlane'd before its owner's fma
        //      overwrites it, and dead rows are never selected again) ----
        const float mA = aA[k] * __builtin_amdgcn_rcpf(pvA);
        const float mB = aB[k] * __builtin_amdgcn_rcpf(pvB);

        // ---- fused rank-1 updates: two independent readlane+fma streams ----
        #pragma unroll
        for (int j = k + 1; j < N; ++j) {
            const float uvA = lanebcastf(aA[j], psA);
            const float uvB = lanebcastf(aB[j], psB);
            aA[j] = __builtin_fmaf(-mA, uvA, aA[j]);
            aB[j] = __builtin_fmaf(-mB, uvB, aB[j]);
        }
    }

    if (lane == 0) {
        const float sgn =
            (((sbits >> 31) ^ ((unsigned)inv & 1u)) != 0u) ? -1.0f : 1.0f;
        out[wid] = sgn;                                        // sign_up * sign_dn
        out[BATCH + wid] = l2sum * 0.69314718055994530942f;    // ln from log2
    }
}

extern "C" void kernel_launch(void* const* d_in, const int* in_sizes, int n_in,
                              void* d_out, int out_size, void* d_ws, size_t ws_size,
                              hipStream_t stream) {
    const float* U      = (const float*)d_in[0];
    const int*   idx_up = (const int*)d_in[1];
    const int*   idx_dn = (const int*)d_in[2];
    float* out = (float*)d_out;

    dim3 block(64);                  // one wave per block, 1 sample per wave
    dim3 grid(BATCH);                // 4096 waves, exact cover
    hipLaunchKernelGGL(restricted_det_kernel, grid, block, 0, stream,
                       U, idx_up, idx_dn, out);
}

// Round 8
// 160.589 us; speedup vs baseline: 1.1624x; 1.1624x over previous
//
#include <hip/hip_runtime.h>

#define BATCH 4096
#define N 64

// One DPP unsigned-max step: x = max(x, dpp_move(x)). VALU only.
template<int CTRL>
__device__ __forceinline__ unsigned dpp_umax(unsigned x) {
    unsigned moved = (unsigned)__builtin_amdgcn_update_dpp(0, (int)x, CTRL, 0xf, 0xf, true);
    return (moved > x) ? moved : x;
}

// Broadcast float from wave-uniform lane ps via v_readlane (SGPR result).
__device__ __forceinline__ float lanebcastf(float v, int ps) {
    return __uint_as_float(__builtin_amdgcn_readlane(__float_as_uint(v), ps));
}

// Packed-key argmax over live lanes: key = (bits(|col|) & ~63) | lane is
// monotone in |col| for floats >= 0, so one umax tree + one readlane yields
// max AND pivot lane. Returns wave-uniform pivot lane.
__device__ __forceinline__ int pivot_argmax(float col, bool alive, int lane) {
    unsigned t = (__float_as_uint(col) & 0x7FFFFFC0u) | (unsigned)lane;
    unsigned r = alive ? t : 0u;
    r = dpp_umax<0x111>(r);   // row_shr:1
    r = dpp_umax<0x112>(r);   // row_shr:2
    r = dpp_umax<0x114>(r);   // row_shr:4
    r = dpp_umax<0x118>(r);   // row_shr:8
    r = dpp_umax<0x142>(r);   // row_bcast:15
    r = dpp_umax<0x143>(r);   // row_bcast:31
    return (int)(((unsigned)__builtin_amdgcn_readlane((int)r, 63)) & 63u);
}

// LOOKAHEAD LU: at step k, update column k+1 FIRST, issue argmax(k+1), then
// run the bulk trailing update (cols k+2..63). The serial pivot chain
// (6 dep DPP + readlane + hazards + rcp) is then hidden under ~120
// independent readlane/fma instructions instead of sitting on the critical
// path (rounds 3-7: ~585 cyc/step observed vs ~176 ideal; the gap is this
// chain -- the compiler cannot do this reorder itself because the j-loop
// writes a[k+1] before argmax(k+1) reads it).
__global__ __launch_bounds__(64) void restricted_det_kernel(
    const float* __restrict__ U,
    const int* __restrict__ idx_up,
    const int* __restrict__ idx_dn,
    float* __restrict__ out)
{
    const int lane = threadIdx.x;      // 0..63, one wave per block
    const int wid  = blockIdx.x;       // sample id

    const int site0 = idx_up[wid * N + lane];
    const int site1 = idx_dn[wid * N + lane];

    float l2sum = 0.0f;                // sum log2|pivot| over both dets
    unsigned sbits = 0u;               // xor of pivot sign bits (uniform)
    int inv = 0;                       // inversion count (uniform)

    #pragma unroll 1
    for (int spin = 0; spin < 2; ++spin) {
        const int site = (spin == 0) ? site0 : site1;

        // lane i holds row i of the gathered matrix, in registers
        float a[N];
        const float4* __restrict__ row = reinterpret_cast<const float4*>(U + (long)site * N);
        #pragma unroll
        for (int q = 0; q < N / 4; ++q) {
            float4 v = row[q];
            a[4*q+0]=v.x; a[4*q+1]=v.y; a[4*q+2]=v.z; a[4*q+3]=v.w;
        }

        unsigned long long chosen = 0ull;
        bool alive = true;

        // prologue: pivot for k=0
        int ps = pivot_argmax(a[0], alive, lane);

        #pragma unroll
        for (int k = 0; k < N - 1; ++k) {
            // ---- bookkeeping for step k (SALU, off-chain) ----
            inv += __popcll(chosen >> ps);
            chosen |= (1ull << ps);
            alive = alive && (lane != ps);

            const float pv = lanebcastf(a[k], ps);
            sbits ^= __float_as_uint(pv) & 0x80000000u;
            l2sum += __log2f(__builtin_fabsf(pv));

            // dead/pivot lanes free-run on garbage; safe: each pivot-row elem
            // is readlane'd before its owner's fma overwrites it, and dead
            // rows are never selected again.
            const float m = a[k] * __builtin_amdgcn_rcpf(pv);

            // ---- lookahead: update col k+1 only, then start its argmax ----
            {
                const float uv = lanebcastf(a[k + 1], ps);
                a[k + 1] = __builtin_fmaf(-m, uv, a[k + 1]);
            }
            const int ps_next = pivot_argmax(a[k + 1], alive, lane);

            // ---- bulk trailing update: cols k+2..63 (hides the chain) ----
            #pragma unroll
            for (int j = k + 2; j < N; ++j) {
                const float uv = lanebcastf(a[j], ps);
                a[j] = __builtin_fmaf(-m, uv, a[j]);
            }

            ps = ps_next;
        }

        // epilogue: last pivot (k = 63)
        inv += __popcll(chosen >> ps);
        chosen |= (1ull << ps);
        const float pv = lanebcastf(a[N - 1], ps);
        sbits ^= __float_as_uint(pv) & 0x80000000u;
        l2sum += __log2f(__builtin_fabsf(pv));
    }

    if (lane == 0) {
        const float sgn =
            (((sbits >> 31) ^ ((unsigned)inv & 1u)) != 0u) ? -1.0f : 1.0f;
        out[wid] = sgn;                                        // sign_up * sign_dn
        out[BATCH + wid] = l2sum * 0.69314718055994530942f;    // ln from log2
    }
}

extern "C" void kernel_launch(void* const* d_in, const int* in_sizes, int n_in,
                              void* d_out, int out_size, void* d_ws, size_t ws_size,
                              hipStream_t stream) {
    const float* U      = (const float*)d_in[0];
    const int*   idx_up = (const int*)d_in[1];
    const int*   idx_dn = (const int*)d_in[2];
    float* out = (float*)d_out;

    dim3 block(64);                  // one wave per block, 1 sample per wave
    dim3 grid(BATCH);                // 4096 waves, exact cover
    hipLaunchKernelGGL(restricted_det_kernel, grid, block, 0, stream,
                       U, idx_up, idx_dn, out);
}